// Round 5
// baseline (551.097 us; speedup 1.0000x reference)
//
#include <hip/hip_runtime.h>
#include <cstdint>
#include <cstddef>

// Problem constants: x[8192,4096]f32, Wp[4096,2048]i32(1 byte each),
// scales[4096,32]f32, group=128, out[8192,4096]f32.
#define TOKENS 8192
#define IN_F   4096
#define OUT_F  4096

typedef __bf16 bf16;
typedef bf16  bf16x8 __attribute__((ext_vector_type(8)));
typedef float f32x4  __attribute__((ext_vector_type(4)));

// ---------------- merged pre-pass: x f32->bf16 AND int4 W -> bf16 ----------------
__global__ void prep_kernel(const float* __restrict__ xin, bf16* __restrict__ xout,
                            const int* __restrict__ wp, const float* __restrict__ sc,
                            bf16* __restrict__ wout) {
    if (blockIdx.x < 16384) {
        size_t i = ((size_t)blockIdx.x * 256 + threadIdx.x) * 8;
        const float4* p = (const float4*)(xin + i);
        float4 a = p[0], b = p[1];
        bf16x8 r;
        r[0] = (bf16)a.x; r[1] = (bf16)a.y; r[2] = (bf16)a.z; r[3] = (bf16)a.w;
        r[4] = (bf16)b.x; r[5] = (bf16)b.y; r[6] = (bf16)b.z; r[7] = (bf16)b.w;
        *(bf16x8*)(xout + i) = r;
    } else {
        int t  = (blockIdx.x - 16384) * 256 + threadIdx.x;
        int j0 = t << 2;
        int n  = j0 >> 11;
        int g  = (j0 & 2047) >> 6;
        float s = sc[(n << 5) + g];
        int4 p = *(const int4*)(wp + j0);
        bf16x8 r;
        r[0] = (bf16)((float)((p.x & 15) - 8) * s);
        r[1] = (bf16)((float)(((p.x >> 4) & 15) - 8) * s);
        r[2] = (bf16)((float)((p.y & 15) - 8) * s);
        r[3] = (bf16)((float)(((p.y >> 4) & 15) - 8) * s);
        r[4] = (bf16)((float)((p.z & 15) - 8) * s);
        r[5] = (bf16)((float)(((p.z >> 4) & 15) - 8) * s);
        r[6] = (bf16)((float)((p.w & 15) - 8) * s);
        r[7] = (bf16)((float)(((p.w >> 4) & 15) - 8) * s);
        *(bf16x8*)(wout + ((size_t)j0 << 1)) = r;
    }
}

// ---------------- main GEMM: 256x256 tile, BK=64, 4 waves, 128x128/wave ----------------
// LDS-BW model: 8-wave 2x4 grid reads 196KiB/CU/K-tile (A amp x4, B amp x2) ->
// 1016-cyc floor vs 628-cyc MFMA = 62% MfmaUtil ceiling (matches r2/r4 measurements).
// 4-wave 2x2 grid, 128x128/wave: reads 128KiB + writes 64KiB -> 768-cyc floor (-25%).
// acc = 8x8 f32x4 = 256 VGPR -> 1 wave/SIMD (launch_bounds(256,1), 512-VGPR budget).
// Single-wave stall exposure is handled by reading every fragment >=1 phase before
// its consuming MFMA cluster (which is now 32 MFMA = ~155 cyc of cover).
//
// Per K-tile, 4 phases, 1 barrier each:
//  ph0: read bq1(t) [8]      | ST_B1(next tile, other buf) | BAR | MM(af0,bq0)  32 MFMA
//  ph1: read af1(t) [8]      | ST_A1(next, other buf)      | BAR | MM(af0,bq1)
//  ph2:                      | ST_A0(t+2, this buf)        | BAR | MM(af1,bq0)
//  ph3: vmcnt(8); read af0(t+1), bq0(t+1) [16, other buf]  | BAR | MM(af1,bq1)
// Region/barrier audit (WAR: every stage >=1 barrier after its region's consuming
// MFMA issued; RAW: every read covered by a vmcnt that leaves only the 8 newest
// loads = A0/B0 of tile+2 in flight). Tail its drain with vmcnt(0)/skip stages.

#define GLL(src, dst) __builtin_amdgcn_global_load_lds( \
    (const __attribute__((address_space(1))) void*)(src), \
    (__attribute__((address_space(3))) void*)(dst), 16, 0, 0)
#define BARX() { __builtin_amdgcn_s_barrier(); __builtin_amdgcn_sched_barrier(0); }

__global__ __launch_bounds__(256, 1)
void gemm_kernel(const bf16* __restrict__ A, const bf16* __restrict__ B,
                 float* __restrict__ C) {
    __shared__ char smem[131072] __attribute__((aligned(128)));

    const int tid  = threadIdx.x;
    const int lane = tid & 63;
    const int w    = tid >> 6;              // 0..3
    const int wr   = w >> 1, wc = w & 1;
    const int lrow = lane >> 3;             // row within an 8-row stage block
    const int gsw  = (lane & 7) ^ lrow;     // pre-swizzled global chunk within 128B row

    // bijective XCD swizzle (512 % 8 == 0)
    const int wg = ((blockIdx.x & 7) << 6) | (blockIdx.x >> 3);
    const int mt = wg >> 4;                 // 32 M-tiles
    const int nt = wg & 15;                 // 16 N-tiles

    const char* Abase = (const char*)A + (size_t)(mt * 256) * (IN_F * 2);
    const char* Bbase = (const char*)B + (size_t)(nt * 256) * (IN_F * 2);

    // quarter q = rows [q*64, q*64+64); wave w stages rows q*64 + w*16 + i*8 + lrow
    const char* gA[4][2]; const char* gB[4][2];
#pragma unroll
    for (int q = 0; q < 4; ++q)
#pragma unroll
        for (int i = 0; i < 2; ++i) {
            gA[q][i] = Abase + (size_t)(q * 64 + w * 16 + i * 8 + lrow) * (IN_F * 2) + gsw * 16;
            gB[q][i] = Bbase + (size_t)(q * 64 + w * 16 + i * 8 + lrow) * (IN_F * 2) + gsw * 16;
        }

    char* const sm = smem;
    // LDS: buf b at b*65536; A rows 0..255 x 128B at +0, B at +32768.
#define ST_Aq(b, q, kt) { GLL(gA[q][0] + (kt) * 128, sm + (b) * 65536 + (q) * 8192 + w * 2048); \
                          GLL(gA[q][1] + (kt) * 128, sm + (b) * 65536 + (q) * 8192 + w * 2048 + 1024); }
#define ST_Bq(b, q, kt) { GLL(gB[q][0] + (kt) * 128, sm + (b) * 65536 + 32768 + (q) * 8192 + w * 2048); \
                          GLL(gB[q][1] + (kt) * 128, sm + (b) * 65536 + 32768 + (q) * 8192 + w * 2048 + 1024); }
#define ST_A0(b, kt) { ST_Aq(b, 0, kt); ST_Aq(b, 2, kt); }   // rows {0-63,128-191}
#define ST_A1(b, kt) { ST_Aq(b, 1, kt); ST_Aq(b, 3, kt); }   // rows {64-127,192-255}
#define ST_B0(b, kt) { ST_Bq(b, 0, kt); ST_Bq(b, 2, kt); }   // cols {0-63,128-191}
#define ST_B1(b, kt) { ST_Bq(b, 1, kt); ST_Bq(b, 3, kt); }   // cols {64-127,192-255}

    const int m_lane = lane & 15, quad = lane >> 4, sw = m_lane & 7;
    const bf16x8* pA0 = (const bf16x8*)sm;
    const bf16x8* pB0 = (const bf16x8*)(sm + 32768);
    const bf16x8* pA1 = (const bf16x8*)(sm + 65536);
    const bf16x8* pB1 = (const bf16x8*)(sm + 98304);

    f32x4 acc[8][8];
#pragma unroll
    for (int i = 0; i < 8; ++i)
#pragma unroll
        for (int j = 0; j < 8; ++j) acc[i][j] = (f32x4)0.0f;

    // prologue: tile0 fully -> buf0; tile1's A0/B0 -> buf1 (stay in flight)
    ST_A0(0, 0); ST_B0(0, 0); ST_B1(0, 0); ST_A1(0, 0);
    ST_A0(1, 1); ST_B0(1, 1);
    asm volatile("s_waitcnt vmcnt(8)" ::: "memory");
    __builtin_amdgcn_s_barrier();

    // A-frag quadrant qr: rows wr*128 + qr*64 + [0,63]; B quadrant qc analog.
#define LDA(dst, PA, qr) \
    { _Pragma("unroll") for (int i = 0; i < 4; ++i) { \
        _Pragma("unroll") for (int kh = 0; kh < 2; ++kh) { \
            dst[i][kh] = (PA)[(wr * 128 + ((qr) * 4 + i) * 16 + m_lane) * 8 + ((kh * 4 + quad) ^ sw)]; } } }
#define LDB(dst, PB, qc) \
    { _Pragma("unroll") for (int j = 0; j < 4; ++j) { \
        _Pragma("unroll") for (int kh = 0; kh < 2; ++kh) { \
            dst[j][kh] = (PB)[(wc * 128 + ((qc) * 4 + j) * 16 + m_lane) * 8 + ((kh * 4 + quad) ^ sw)]; } } }
#define MM(afv, bv, qr, qc) \
    { __builtin_amdgcn_s_setprio(1); \
      _Pragma("unroll") for (int i = 0; i < 4; ++i) { \
        _Pragma("unroll") for (int j = 0; j < 4; ++j) { \
          _Pragma("unroll") for (int kh = 0; kh < 2; ++kh) { \
            acc[(qr) * 4 + i][(qc) * 4 + j] = __builtin_amdgcn_mfma_f32_16x16x32_bf16( \
                afv[i][kh], bv[j][kh], acc[(qr) * 4 + i][(qc) * 4 + j], 0, 0, 0); } } } \
      __builtin_amdgcn_s_setprio(0); }

    bf16x8 af0[4][2], af1[4][2], bq0[4][2], bq1[4][2];
    LDA(af0, pA0, 0); LDB(bq0, pB0, 0);       // preload tile0's ph0 operands

    for (int it = 0; it < 32; ++it) {
        const int kt0 = 2 * it;
        const int kt1 = kt0 + 1;
        const bool more = (it < 31);
        {   // ---- tile kt0 from buf0 ----
            LDB(bq1, pB0, 1);                  // ph0: for MM(ph1)
            ST_B1(1, kt1);
            BARX(); MM(af0, bq0, 0, 0);
            LDA(af1, pA0, 1);                  // ph1: for MM(ph2/ph3)
            ST_A1(1, kt1);
            BARX(); MM(af0, bq1, 0, 1);
            if (more) ST_A0(0, kt0 + 2);       // ph2 (A0 drained since MM ph0)
            BARX(); MM(af1, bq0, 1, 0);
            if (more) {                        // ph3
                ST_B0(0, kt0 + 2);
                asm volatile("s_waitcnt vmcnt(8)" ::: "memory");
            } else {
                asm volatile("s_waitcnt vmcnt(0)" ::: "memory");
            }
            LDA(af0, pA1, 0); LDB(bq0, pB1, 0);  // prefetch tile kt1 (landed: see hdr)
            BARX(); MM(af1, bq1, 1, 1);
        }
        {   // ---- tile kt1 from buf1 ----
            LDB(bq1, pB1, 1);                  // ph0
            if (more) ST_B1(0, kt1 + 1);
            BARX(); MM(af0, bq0, 0, 0);
            LDA(af1, pA1, 1);                  // ph1
            if (more) ST_A1(0, kt1 + 1);
            BARX(); MM(af0, bq1, 0, 1);
            if (more) ST_A0(1, kt1 + 2);       // ph2
            BARX(); MM(af1, bq0, 1, 0);
            if (more) {                        // ph3
                ST_B0(1, kt1 + 2);
                asm volatile("s_waitcnt vmcnt(8)" ::: "memory");
                LDA(af0, pA0, 0); LDB(bq0, pB0, 0);  // prefetch next kt0
            }
            BARX(); MM(af1, bq1, 1, 1);
        }
    }

    // epilogue: C/D layout col=lane&15, row=quad*4+reg (m89-verified)
    const size_t crow0 = (size_t)(mt * 256 + wr * 128 + quad * 4) * OUT_F
                       + (size_t)(nt * 256 + wc * 128 + m_lane);
#pragma unroll
    for (int i = 0; i < 8; ++i)
#pragma unroll
        for (int r = 0; r < 4; ++r) {
            float* cp = C + crow0 + (size_t)(i * 16 + r) * OUT_F;
#pragma unroll
            for (int j = 0; j < 8; ++j) cp[j * 16] = acc[i][j][r];
        }
}

// ---------------- fallback (only if ws too small): slow but correct ----------------
__global__ void naive_kernel(const float* __restrict__ x, const int* __restrict__ wp,
                             const float* __restrict__ sc, float* __restrict__ out) {
    int o = blockIdx.x * 256 + threadIdx.x;
    int t = o >> 12, n = o & 4095;
    const float* xr = x + (size_t)t * IN_F;
    const int*   wr2 = wp + (size_t)n * (IN_F / 2);
    float acc = 0.f;
    for (int g = 0; g < 32; ++g) {
        float s = sc[n * 32 + g];
        float part = 0.f;
        for (int j = 0; j < 64; ++j) {
            int p = wr2[g * 64 + j];
            part += xr[g * 128 + 2 * j]     * (float)((p & 15) - 8);
            part += xr[g * 128 + 2 * j + 1] * (float)(((p >> 4) & 15) - 8);
        }
        acc += part * s;
    }
    out[o] = acc;
}

extern "C" void kernel_launch(void* const* d_in, const int* in_sizes, int n_in,
                              void* d_out, int out_size, void* d_ws, size_t ws_size,
                              hipStream_t stream) {
    const float* x  = (const float*)d_in[0];
    const int*   wp = (const int*)d_in[1];
    const float* sc = (const float*)d_in[2];
    float* out = (float*)d_out;

    const size_t xb_bytes = (size_t)TOKENS * IN_F * 2;   // 64 MiB
    const size_t wb_bytes = (size_t)OUT_F * IN_F * 2;    // 32 MiB

    if (ws_size >= xb_bytes + wb_bytes) {
        bf16* xb = (bf16*)d_ws;
        bf16* wb = (bf16*)((char*)d_ws + xb_bytes);
        prep_kernel<<<dim3(16384 + 8192), dim3(256), 0, stream>>>(x, xb, wp, sc, wb);
        gemm_kernel<<<dim3((TOKENS / 256) * (OUT_F / 256)), dim3(256), 0, stream>>>(xb, wb, out);
    } else {
        naive_kernel<<<dim3((TOKENS * OUT_F) / 256), dim3(256), 0, stream>>>(x, wp, sc, out);
    }
}